// Round 9
// baseline (192758.154 us; speedup 1.0000x reference)
//
#include <hip/hip_runtime.h>
#include <hip/hip_bf16.h>
#include <stdint.h>

#define SEQ     8192
#define DIM     2048
#define HID     1024
#define NWG     256
#define CPW     8      // output columns per workgroup

typedef unsigned long long u64;
typedef __attribute__((ext_vector_type(4))) unsigned int u32x4;

// ---- workspace layout (bytes) ----
//   0     : Hbuf[1024] (u32 {bf16 val | u16 tag}) -- hidden, tag = t+1 when written
//   4096  : bufA[2048] (u32 tagged)  -- layers 0,2 write; 1,3 read
//   12288 : bufB[2048] (u32 tagged)  -- layers 1,3 write; 2,4 read
//   memset first 20480 B per call: val=0bf16, tag=0 == "H ready for t=0"
//
// Tags: layer-l output of step t carries tag 4t+l+1 (l=0..3); H carries t+1.
// Max tag 4*8191+4 = 32768 < 2^16; poll compare is wrap-safe (>=) anyway.
//
// Poll (R5-proven, register-safe): issue 2x dwordx4 -> s_waitcnt vmcnt(0) +
// sched_barrier -> check tags -> s_sleep+retry. The drain happens in the SAME
// iteration before any use, so no compiler-inserted copy can read an
// in-flight VGPR (the R6/R7 pipelined-poll UB, now removed).
//
// Safety without a per-phase workgroup barrier (LDS quarter-flags):
//  - value+tag share one u32 (un-torn store): consumer observing tag p implies
//    the producer's store committed, hence the producer finished reading its
//    own inputs (program order, loads drained before store issue).
//  - intra-WG: each wave ds_writes its staged quarter, drains lgkmcnt, then
//    ds_writes its parity flag; LDS ops execute in order per wave, so a wave
//    observing the flag sees the staged data. A wave's phase-p publish store
//    follows FMAs that required all 4 phase-p flags, so it happens-after all
//    4 waves' phase-p polls.
//  - cross-WG ping-pong (period 2): a slot is overwritten at phase p+2 only
//    by a WG whose 4 waves jointly observed every WG's phase-p+1 tags, which
//    transitively happens-after every phase-p+1 (and earlier) read of that
//    slot. Induction also gives: no consumer can observe a tag NEWER than its
//    target (that tag's existence implies this very poll already succeeded).
//  - flag slot (parity) reuse at p+2 requires all 4 waves past p+1 staging,
//    hence past p compute: exact-match spin cannot be skipped (no ABA). R7
//    completing (no deadlock) is empirical evidence this ordering holds.

__device__ __forceinline__ uint16_t f2bf(float f) {
  union { float f; uint32_t u; } v; v.f = f;
  uint32_t r = v.u + 0x7FFFu + ((v.u >> 16) & 1u);   // round-to-nearest-even
  return (uint16_t)(r >> 16);
}
__device__ __forceinline__ float bf2f(uint16_t u) {
  union { uint32_t u; float f; } v; v.u = ((uint32_t)u) << 16; return v.f;
}

__device__ __forceinline__ void cstore64(u64* p, u64 v) {
  __hip_atomic_store(p, v, __ATOMIC_RELAXED, __HIP_MEMORY_SCOPE_AGENT);
}
// pack two tagged bf16 values (adjacent columns) into one 8B store
__device__ __forceinline__ u64 pack2(float v0, float v1, uint32_t tag) {
  const uint32_t w0 = (uint32_t)f2bf(v0) | (tag << 16);
  const uint32_t w1 = (uint32_t)f2bf(v1) | (tag << 16);
  return ((u64)w1 << 32) | (u64)w0;
}

// 16B coherent load (sc0 sc1 -> serviced at the coherent point, bypasses the
// non-coherent per-XCD L2). Result valid only after an explicit s_waitcnt.
__device__ __forceinline__ u32x4 cload128(const void* p) {
  u32x4 r;
  asm volatile("global_load_dwordx4 %0, %1, off sc0 sc1"
               : "=v"(r) : "v"(p) : "memory");
  return r;
}
__device__ __forceinline__ void vm_drain() {
  asm volatile("s_waitcnt vmcnt(0)" ::: "memory");
  __builtin_amdgcn_sched_barrier(0);
}

// R5-proven poll of this lane's 8 tagged u32 (32B), decode into LDS dest.
__device__ __forceinline__ void poll_stage(const uint32_t* __restrict__ p,
                                           uint16_t tgt, bool relu,
                                           float* __restrict__ d) {
  u32x4 a, b;
  for (;;) {
    a = cload128(p);
    b = cload128(p + 4);
    vm_drain();
    bool ok = true;
    #pragma unroll
    for (int i = 0; i < 4; ++i) {
      ok &= (uint16_t)((uint16_t)(a[i] >> 16) - tgt) < 0x8000u;
      ok &= (uint16_t)((uint16_t)(b[i] >> 16) - tgt) < 0x8000u;
    }
    if (__all(ok)) break;
    __builtin_amdgcn_s_sleep(1);
  }
  #pragma unroll
  for (int i = 0; i < 4; ++i) {
    float fa = __uint_as_float(a[i] << 16);     // bf16 -> f32
    float fb = __uint_as_float(b[i] << 16);
    if (relu) { fa = fmaxf(fa, 0.f); fb = fmaxf(fb, 0.f); }
    d[i]     = fa;
    d[4 + i] = fb;
  }
}

__global__ void __launch_bounds__(256, 1)
rnn_persist(const float* __restrict__ x, const float* __restrict__ W0,
            const float* __restrict__ b0, const float* __restrict__ Wmid,
            const float* __restrict__ bmid, const float* __restrict__ Wf,
            const float* __restrict__ bfv, float* __restrict__ out,
            uint32_t* __restrict__ Hbuf, uint32_t* __restrict__ bufA,
            uint32_t* __restrict__ bufB)
{
  __shared__ uint16_t wlds[4 * CPW * DIM];   // layers 0-3 weights, 128 KiB
  __shared__ float    sAct[2][DIM];          // double-buffered staged acts, 16 KiB
  __shared__ uint32_t sflag[2][4];           // per-parity per-quarter ready flags

  const int tid  = threadIdx.x;
  const int wg   = blockIdx.x;
  const int wave = tid >> 6;
  const int lane = tid & 63;

  // each wave owns 2 adjacent output columns of every layer
  const int cidx0 = wave * 2;
  const int col0  = wg * CPW + cidx0;
  const int col1  = col0 + 1;

  // ---- stage layers 0-3 weight slice (bf16) into LDS, once ----
  for (int i = tid; i < 4 * CPW * DIM; i += 256) {
    const int l = i >> 14;           // / (CPW*DIM)
    const int r = i & 16383;
    const int k = r >> 3;            // 0..2047
    const int c = r & 7;             // 0..7
    const float* Ws = (l == 0) ? W0 : (Wmid + (size_t)(l - 1) * DIM * DIM);
    wlds[(l * CPW + c) * DIM + k] = f2bf(Ws[(size_t)k * DIM + (wg * CPW + c)]);
  }
  // ---- layer-4 weights into registers, own-quarter-relative order so all
  //      register indices stay compile-time (rule #20) ----
  ushort4 wf0[8], wf1[8];
  #pragma unroll
  for (int qi = 0; qi < 4; ++qi) {
    const int q = (wave + qi) & 3;
    #pragma unroll
    for (int jj = 0; jj < 2; ++jj) {
      const int k = (2 * q + jj) * 256 + lane * 4;
      ushort4 a, b;
      a.x = f2bf(Wf[(size_t)(k + 0) * DIM + col0]);
      a.y = f2bf(Wf[(size_t)(k + 1) * DIM + col0]);
      a.z = f2bf(Wf[(size_t)(k + 2) * DIM + col0]);
      a.w = f2bf(Wf[(size_t)(k + 3) * DIM + col0]);
      b.x = f2bf(Wf[(size_t)(k + 0) * DIM + col1]);
      b.y = f2bf(Wf[(size_t)(k + 1) * DIM + col1]);
      b.z = f2bf(Wf[(size_t)(k + 2) * DIM + col1]);
      b.w = f2bf(Wf[(size_t)(k + 3) * DIM + col1]);
      wf0[qi * 2 + jj] = a;
      wf1[qi * 2 + jj] = b;
    }
  }

  float bias0[5], bias1[5];
  bias0[0] = b0[col0];              bias1[0] = b0[col1];
  bias0[1] = bmid[0 * DIM + col0];  bias1[1] = bmid[0 * DIM + col1];
  bias0[2] = bmid[1 * DIM + col0];  bias1[2] = bmid[1 * DIM + col1];
  bias0[3] = bmid[2 * DIM + col0];  bias1[3] = bmid[2 * DIM + col1];
  bias0[4] = bfv[col0];             bias1[4] = bfv[col1];

  if (tid < 8) sflag[tid >> 2][tid & 3] = 0;
  __syncthreads();   // weights + flag init visible (only barrier in the kernel)

  const bool hWG = (wg < 128);   // layer-4 cols of this WG are H (else outputs)
  uint32_t ph = 0;               // global phase index = 5t + l

  for (int t = 0; t < SEQ; ++t) {
    const float* __restrict__ xrow = x + (size_t)t * HID;

    #pragma unroll
    for (int l = 0; l < 5; ++l) {
      const int par = (int)(ph & 1u);
      float* __restrict__ sa = sAct[par];
      const uint32_t want = ph + 1u;

      // ============ stage own quarter into sa, then set LDS flag ============
      float* __restrict__ dq = sa + wave * 512 + lane * 8;
      if (l == 0) {
        if (wave < 2) {
          const float4 a0 = *(const float4*)(xrow + wave * 512 + lane * 8);
          const float4 a1 = *(const float4*)(xrow + wave * 512 + lane * 8 + 4);
          *(float4*)dq       = a0;
          *(float4*)(dq + 4) = a1;
        } else {
          poll_stage(Hbuf + (wave - 2) * 512 + lane * 8, (uint16_t)t,
                     false, dq);                        // hidden: no relu
        }
      } else {
        const uint32_t* __restrict__ src = (l & 1) ? bufA : bufB;
        poll_stage(src + wave * 512 + lane * 8,
                   (uint16_t)(4u * (uint32_t)t + (uint32_t)l), true, dq);
      }
      asm volatile("s_waitcnt lgkmcnt(0)" ::: "memory");  // staged data in LDS
      __builtin_amdgcn_sched_barrier(0);
      if (lane == 0)
        __hip_atomic_store(&sflag[par][wave], want, __ATOMIC_RELAXED,
                           __HIP_MEMORY_SCOPE_WORKGROUP);

      // ===== compute: quarters in own-first order, spin per-quarter flag =====
      float acc0 = 0.f, acc1 = 0.f;
      const uint16_t* w0p = wlds + ((l * CPW + cidx0) * DIM);
      const uint16_t* w1p = w0p + DIM;
      #pragma unroll
      for (int qi = 0; qi < 4; ++qi) {
        const int q = (wave + qi) & 3;
        if (qi > 0) {   // own quarter's flag was set by this wave already
          while (__hip_atomic_load(&sflag[par][q], __ATOMIC_RELAXED,
                                   __HIP_MEMORY_SCOPE_WORKGROUP) != want) {}
          asm volatile("" ::: "memory");
          __builtin_amdgcn_sched_barrier(0);
        }
        #pragma unroll
        for (int jj = 0; jj < 2; ++jj) {
          const int kb = (2 * q + jj) * 256 + lane * 4;
          const float4 a = *(const float4*)&sa[kb];
          ushort4 wa, wb;
          if (l < 4) {
            wa = *(const ushort4*)(w0p + kb);
            wb = *(const ushort4*)(w1p + kb);
          } else {
            wa = wf0[qi * 2 + jj];   // compile-time register index
            wb = wf1[qi * 2 + jj];
          }
          acc0 = fmaf(a.x, bf2f(wa.x), acc0); acc1 = fmaf(a.x, bf2f(wb.x), acc1);
          acc0 = fmaf(a.y, bf2f(wa.y), acc0); acc1 = fmaf(a.y, bf2f(wb.y), acc1);
          acc0 = fmaf(a.z, bf2f(wa.z), acc0); acc1 = fmaf(a.z, bf2f(wb.z), acc1);
          acc0 = fmaf(a.w, bf2f(wa.w), acc0); acc1 = fmaf(a.w, bf2f(wb.w), acc1);
        }
      }
      #pragma unroll
      for (int off = 32; off > 0; off >>= 1) {
        acc0 += __shfl_xor(acc0, off, 64);
        acc1 += __shfl_xor(acc1, off, 64);
      }

      // ============ publish: tagged 8B store, fire-and-continue ============
      if (lane == 0) {
        const float v0 = acc0 + bias0[l];
        const float v1 = acc1 + bias1[l];
        if (l < 4) {
          uint32_t* dst = (l & 1) ? bufB : bufA;
          cstore64((u64*)dst + (col0 >> 1),
                   pack2(v0, v1, 4u * (uint32_t)t + (uint32_t)l + 1u));
        } else if (hWG) {
          if (t < SEQ - 1) {
            cstore64((u64*)Hbuf + (col0 >> 1), pack2(v0, v1, (uint32_t)t + 1u));
          } else {
            float2 o; o.x = v0; o.y = v1;
            *(float2*)(out + col0) = o;                          // final hidden
          }
        } else {
          float2 o; o.x = v0; o.y = v1;
          *(float2*)(out + HID + (size_t)t * HID + (col0 - HID)) = o;  // outputs[t]
        }
      }
      ++ph;
      // no fence, no global flag, no barrier
    }
  }
}

extern "C" void kernel_launch(void* const* d_in, const int* in_sizes, int n_in,
                              void* d_out, int out_size, void* d_ws, size_t ws_size,
                              hipStream_t stream) {
  (void)in_sizes; (void)n_in; (void)out_size; (void)ws_size;
  const float* x    = (const float*)d_in[0];
  const float* W0   = (const float*)d_in[1];
  const float* b0   = (const float*)d_in[2];
  const float* Wmid = (const float*)d_in[3];
  const float* bmid = (const float*)d_in[4];
  const float* Wf   = (const float*)d_in[5];
  const float* bfv  = (const float*)d_in[6];
  float* out = (float*)d_out;

  uint8_t* ws = (uint8_t*)d_ws;
  uint32_t* Hbuf = (uint32_t*)(ws + 0);
  uint32_t* bufA = (uint32_t*)(ws + 4096);
  uint32_t* bufB = (uint32_t*)(ws + 12288);

  // reset tags + hidden every call: {bf16 0.0, tag 0} == "H ready for t=0"
  hipMemsetAsync(d_ws, 0, 20480, stream);

  rnn_persist<<<dim3(NWG), dim3(256), 0, stream>>>(
      x, W0, b0, Wmid, bmid, Wf, bfv, out, Hbuf, bufA, bufB);
}

// Round 10
// 186893.481 us; speedup vs baseline: 1.0314x; 1.0314x over previous
//
#include <hip/hip_runtime.h>
#include <hip/hip_bf16.h>
#include <stdint.h>

#define SEQ     8192
#define DIM     2048
#define HID     1024
#define NWG     256
#define CPW     8      // output columns per workgroup
#define RDEPTH  4      // layer-3 ring depth (steps)

typedef unsigned long long u64;
typedef __attribute__((ext_vector_type(4))) unsigned int u32x4;

// ---- workspace layout (bytes) ----
//   0     : Hbuf[1024]        (u32 {bf16 val | u16 tag}) tag = t+1 when written
//   4096  : bufA[2048]        layers 0,2 write (tags 4t+1, 4t+3); read at l=1,3
//   12288 : bufB[2048]        layer 1 writes (tag 4t+2); read at l=2
//   20480 : ring[4][2048]     layer 3 writes slot t&3 (tag 4t+4); read at l=4
//   memset first 53248 B per call: val=0bf16, tag=0 == "H ready for t=0"
//
// Tags <= 4*8191+4 = 32768 < 2^16; compares are wrap-safe anyway.
//
// Safety (R5-proven transitive argument, now with ring):
//  - value+tag share one u32 (un-torn): observing tag p implies the producer's
//    store committed, hence the producer finished reading its phase-p inputs.
//  - bufA slot overwrite (l=2, tag 4t+3) happens only after that WG's l=2 poll
//    saw ALL l=1 tags (4t+2), each published after its wave finished reading
//    bufA's 4t+1 data -> no reader can still need the old value. Same chain
//    for every buffer. Consumers can never observe a newer-than-target tag
//    (its existence would imply this very poll already succeeded).
//  - ring depth 4: slot reused after 4 steps (20 phases) -- output WGs (which
//    nothing gates on) would need a 20-phase lag to mis-read; the per-phase
//    poll chain bounds intra-device skew to ~2 phases.
//  - sAct is parity double-buffered: phase p+1 staging never overwrites data
//    still being read by a slow wave's phase-p compute (latent R5 race fixed).

__device__ __forceinline__ uint16_t f2bf(float f) {
  union { float f; uint32_t u; } v; v.f = f;
  uint32_t r = v.u + 0x7FFFu + ((v.u >> 16) & 1u);   // round-to-nearest-even
  return (uint16_t)(r >> 16);
}
__device__ __forceinline__ float bf2f(uint16_t u) {
  union { uint32_t u; float f; } v; v.u = ((uint32_t)u) << 16; return v.f;
}

__device__ __forceinline__ void cstore64(u64* p, u64 v) {
  __hip_atomic_store(p, v, __ATOMIC_RELAXED, __HIP_MEMORY_SCOPE_AGENT);
}
// pack two tagged bf16 values (adjacent columns) into one 8B store
__device__ __forceinline__ u64 pack2(float v0, float v1, uint32_t tag) {
  const uint32_t w0 = (uint32_t)f2bf(v0) | (tag << 16);
  const uint32_t w1 = (uint32_t)f2bf(v1) | (tag << 16);
  return ((u64)w1 << 32) | (u64)w0;
}

// 16B coherent load (sc0 sc1 -> bypasses non-coherent L1/L2, serviced at the
// coherent point/MALL). Result valid only after an explicit s_waitcnt.
__device__ __forceinline__ u32x4 cload128(const void* p) {
  u32x4 r;
  asm volatile("global_load_dwordx4 %0, %1, off sc0 sc1"
               : "=v"(r) : "v"(p) : "memory");
  return r;
}
__device__ __forceinline__ void vm_drain() {
  asm volatile("s_waitcnt vmcnt(0)" ::: "memory");
  __builtin_amdgcn_sched_barrier(0);
}

// R5-proven poll of this lane's 8 tagged u32 (32B) with adaptive backoff:
// if any tag is >=2 phases behind target, sleep; near the endgame, spin at
// RT cadence. Decode into the LDS staging buffer on success.
__device__ __forceinline__ void poll_stage(const uint32_t* __restrict__ p,
                                           uint16_t tgt, bool relu,
                                           float* __restrict__ d) {
  u32x4 a, b;
  for (;;) {
    a = cload128(p);
    b = cload128(p + 4);
    vm_drain();
    bool ok = true, far = false;
    #pragma unroll
    for (int i = 0; i < 4; ++i) {
      const uint16_t da = (uint16_t)(tgt - (uint16_t)(a[i] >> 16));
      const uint16_t db = (uint16_t)(tgt - (uint16_t)(b[i] >> 16));
      // ready: deficit 0 or wrapped (tag newer). far: deficit in [2, 0x8000)
      ok  &= (da == 0) | (da >= 0x8000u);
      ok  &= (db == 0) | (db >= 0x8000u);
      far |= (da >= 2 && da < 0x8000u) | (db >= 2 && db < 0x8000u);
    }
    if (__all(ok)) break;
    if (__any(far)) __builtin_amdgcn_s_sleep(4);   // early: back off ~200ns
  }
  #pragma unroll
  for (int i = 0; i < 4; ++i) {
    float fa = __uint_as_float(a[i] << 16);     // bf16 -> f32
    float fb = __uint_as_float(b[i] << 16);
    if (relu) { fa = fmaxf(fa, 0.f); fb = fmaxf(fb, 0.f); }
    d[i]     = fa;
    d[4 + i] = fb;
  }
}

__global__ void __launch_bounds__(256, 1)
rnn_persist(const float* __restrict__ x, const float* __restrict__ W0,
            const float* __restrict__ b0, const float* __restrict__ Wmid,
            const float* __restrict__ bmid, const float* __restrict__ Wf,
            const float* __restrict__ bfv, float* __restrict__ out,
            uint32_t* __restrict__ Hbuf, uint32_t* __restrict__ bufA,
            uint32_t* __restrict__ bufB, uint32_t* __restrict__ ring)
{
  __shared__ uint16_t wlds[4 * CPW * DIM];   // layers 0-3 weights, 128 KiB
  __shared__ float    sAct[2][DIM];          // parity double-buffered, 16 KiB

  const int tid  = threadIdx.x;
  const int wg   = blockIdx.x;
  const int wave = tid >> 6;
  const int lane = tid & 63;

  // each wave owns 2 adjacent output columns of every layer
  const int cidx0 = wave * 2;
  const int col0  = wg * CPW + cidx0;
  const int col1  = col0 + 1;

  // ---- stage layers 0-3 weight slice (bf16) into LDS, once ----
  for (int i = tid; i < 4 * CPW * DIM; i += 256) {
    const int l = i >> 14;           // / (CPW*DIM)
    const int r = i & 16383;
    const int k = r >> 3;            // 0..2047
    const int c = r & 7;             // 0..7
    const float* Ws = (l == 0) ? W0 : (Wmid + (size_t)(l - 1) * DIM * DIM);
    wlds[(l * CPW + c) * DIM + k] = f2bf(Ws[(size_t)k * DIM + (wg * CPW + c)]);
  }
  // ---- layer-4 weights into registers: 2 cols x 32 k-vals/lane ----
  ushort4 wf0[8], wf1[8];
  #pragma unroll
  for (int j = 0; j < 8; ++j) {
    const int k = j * 256 + lane * 4;
    wf0[j].x = f2bf(Wf[(size_t)(k + 0) * DIM + col0]);
    wf0[j].y = f2bf(Wf[(size_t)(k + 1) * DIM + col0]);
    wf0[j].z = f2bf(Wf[(size_t)(k + 2) * DIM + col0]);
    wf0[j].w = f2bf(Wf[(size_t)(k + 3) * DIM + col0]);
    wf1[j].x = f2bf(Wf[(size_t)(k + 0) * DIM + col1]);
    wf1[j].y = f2bf(Wf[(size_t)(k + 1) * DIM + col1]);
    wf1[j].z = f2bf(Wf[(size_t)(k + 2) * DIM + col1]);
    wf1[j].w = f2bf(Wf[(size_t)(k + 3) * DIM + col1]);
  }
  __syncthreads();

  float bias0[5], bias1[5];
  bias0[0] = b0[col0];              bias1[0] = b0[col1];
  bias0[1] = bmid[0 * DIM + col0];  bias1[1] = bmid[0 * DIM + col1];
  bias0[2] = bmid[1 * DIM + col0];  bias1[2] = bmid[1 * DIM + col1];
  bias0[3] = bmid[2 * DIM + col0];  bias1[3] = bmid[2 * DIM + col1];
  bias0[4] = bfv[col0];             bias1[4] = bfv[col1];

  const bool hWG = (wg < 128);   // layer-4 cols of this WG are H (else outputs)

  // ---- x prefetch registers (used by waves 0-1 only) ----
  float4 xr0, xr1;
  if (wave < 2) {
    const float* xp = x + wave * 512 + lane * 8;     // t = 0
    xr0 = *(const float4*)xp;
    xr1 = *(const float4*)(xp + 4);
  }

  uint32_t ph = 0;   // global phase index = 5t + l

  for (int t = 0; t < SEQ; ++t) {
    #pragma unroll
    for (int l = 0; l < 5; ++l) {
      float* __restrict__ sa = sAct[ph & 1u];

      // ============ stage this wave's quarter into sa ============
      float* __restrict__ dq = sa + wave * 512 + lane * 8;
      if (l == 0) {
        if (wave < 2) {
          // x half from prefetched regs (no memory on the staging path)
          *(float4*)dq       = xr0;
          *(float4*)(dq + 4) = xr1;
          // issue prefetch for next step (drained by compiler before t+1 use)
          const int tn = (t + 1 < SEQ) ? t + 1 : t;
          const float* xp = x + (size_t)tn * HID + wave * 512 + lane * 8;
          xr0 = *(const float4*)xp;
          xr1 = *(const float4*)(xp + 4);
        } else {
          poll_stage(Hbuf + (wave - 2) * 512 + lane * 8, (uint16_t)t,
                     false, dq);                        // hidden: no relu
        }
      } else {
        const uint32_t* src;
        if (l == 1)      src = bufA;                       // layer-0 out, 4t+1
        else if (l == 2) src = bufB;                       // layer-1 out, 4t+2
        else if (l == 3) src = bufA;                       // layer-2 out, 4t+3
        else             src = ring + (size_t)(t & (RDEPTH - 1)) * DIM; // 4t+4
        poll_stage(src + wave * 512 + lane * 8,
                   (uint16_t)(4u * (uint32_t)t + (uint32_t)l), true, dq);
      }
      __syncthreads();   // full vector staged (cross-wave join)

      // ========================== dot products ==========================
      float acc0 = 0.f, acc1 = 0.f;
      if (l < 4) {
        const uint16_t* w0p = wlds + ((l * CPW + cidx0) * DIM);
        const uint16_t* w1p = w0p + DIM;
        #pragma unroll
        for (int j = 0; j < 8; ++j) {
          const int kb = j * 256 + lane * 4;
          const float4  a  = *(const float4*)&sa[kb];
          const ushort4 wa = *(const ushort4*)(w0p + kb);
          const ushort4 wb = *(const ushort4*)(w1p + kb);
          acc0 = fmaf(a.x, bf2f(wa.x), acc0); acc1 = fmaf(a.x, bf2f(wb.x), acc1);
          acc0 = fmaf(a.y, bf2f(wa.y), acc0); acc1 = fmaf(a.y, bf2f(wb.y), acc1);
          acc0 = fmaf(a.z, bf2f(wa.z), acc0); acc1 = fmaf(a.z, bf2f(wb.z), acc1);
          acc0 = fmaf(a.w, bf2f(wa.w), acc0); acc1 = fmaf(a.w, bf2f(wb.w), acc1);
        }
      } else {
        #pragma unroll
        for (int j = 0; j < 8; ++j) {
          const int kb = j * 256 + lane * 4;
          const float4  a  = *(const float4*)&sa[kb];
          const ushort4 wa = wf0[j];
          const ushort4 wb = wf1[j];
          acc0 = fmaf(a.x, bf2f(wa.x), acc0); acc1 = fmaf(a.x, bf2f(wb.x), acc1);
          acc0 = fmaf(a.y, bf2f(wa.y), acc0); acc1 = fmaf(a.y, bf2f(wb.y), acc1);
          acc0 = fmaf(a.z, bf2f(wa.z), acc0); acc1 = fmaf(a.z, bf2f(wb.z), acc1);
          acc0 = fmaf(a.w, bf2f(wa.w), acc0); acc1 = fmaf(a.w, bf2f(wb.w), acc1);
        }
      }
      #pragma unroll
      for (int off = 32; off > 0; off >>= 1) {
        acc0 += __shfl_xor(acc0, off, 64);
        acc1 += __shfl_xor(acc1, off, 64);
      }

      // ============ publish: tagged 8B store, fire-and-continue ============
      if (lane == 0) {
        const float v0 = acc0 + bias0[l];
        const float v1 = acc1 + bias1[l];
        if (l < 3) {
          uint32_t* dst = (l == 1) ? bufB : bufA;
          cstore64((u64*)dst + (col0 >> 1),
                   pack2(v0, v1, 4u * (uint32_t)t + (uint32_t)l + 1u));
        } else if (l == 3) {
          uint32_t* dst = ring + (size_t)(t & (RDEPTH - 1)) * DIM;
          cstore64((u64*)dst + (col0 >> 1),
                   pack2(v0, v1, 4u * (uint32_t)t + 4u));
        } else if (hWG) {
          if (t < SEQ - 1) {
            cstore64((u64*)Hbuf + (col0 >> 1), pack2(v0, v1, (uint32_t)t + 1u));
          } else {
            float2 o; o.x = v0; o.y = v1;
            *(float2*)(out + col0) = o;                          // final hidden
          }
        } else {
          float2 o; o.x = v0; o.y = v1;
          *(float2*)(out + HID + (size_t)t * HID + (col0 - HID)) = o;  // outputs[t]
        }
      }
      ++ph;
    }
  }
}

extern "C" void kernel_launch(void* const* d_in, const int* in_sizes, int n_in,
                              void* d_out, int out_size, void* d_ws, size_t ws_size,
                              hipStream_t stream) {
  (void)in_sizes; (void)n_in; (void)out_size; (void)ws_size;
  const float* x    = (const float*)d_in[0];
  const float* W0   = (const float*)d_in[1];
  const float* b0   = (const float*)d_in[2];
  const float* Wmid = (const float*)d_in[3];
  const float* bmid = (const float*)d_in[4];
  const float* Wf   = (const float*)d_in[5];
  const float* bfv  = (const float*)d_in[6];
  float* out = (float*)d_out;

  uint8_t* ws = (uint8_t*)d_ws;
  uint32_t* Hbuf = (uint32_t*)(ws + 0);
  uint32_t* bufA = (uint32_t*)(ws + 4096);
  uint32_t* bufB = (uint32_t*)(ws + 12288);
  uint32_t* ring = (uint32_t*)(ws + 20480);

  // reset tags + hidden every call: {bf16 0.0, tag 0} == "H ready for t=0"
  hipMemsetAsync(d_ws, 0, 53248, stream);

  rnn_persist<<<dim3(NWG), dim3(256), 0, stream>>>(
      x, W0, b0, Wmid, bmid, Wf, bfv, out, Hbuf, bufA, bufB, ring);
}

// Round 12
// 186159.009 us; speedup vs baseline: 1.0354x; 1.0039x over previous
//
#include <hip/hip_runtime.h>
#include <hip/hip_bf16.h>
#include <stdint.h>

#define SEQ     8192
#define DIM     2048
#define HID     1024
#define NWG     256
#define CPW     8      // output columns per workgroup
#define RDEPTH  4      // layer-3 ring depth (steps)

typedef unsigned long long u64;

// ---- workspace layout (bytes) ----
//   0     : Hbuf[1024]    (u32 {bf16 val | u16 tag}) tag = t+1 when written
//   4096  : bufA[2048]    layers 0,2 write (tags 4t+1, 4t+3); read at l=1,3
//   12288 : bufB[2048]    layer 1 writes (tag 4t+2); read at l=2
//   20480 : ring[4][2048] layer 3 writes slot t&3 (tag 4t+4); read at l=4
//   memset first 53248 B per call: val=0bf16, tag=0 == "H ready for t=0"
//
// Readiness: tags are monotone (max 4*8191+4 = 32768 < 2^16), so a consumer
// with target tag T is ready iff dword >= (T<<16) unsigned: tag==T-1 gives at
// most ((T-1)<<16)|0xFFFF = (T<<16)-1 < thr -- value bits cannot fake it.
// memset gives dword 0: ready only for thr==0 (H at t=0, correct).
//
// Safety chain (R5-proven): value+tag share one u32 (un-torn); observing tag
// p implies the producer's store committed, hence the producer finished
// reading its phase-p inputs (its loads drained before the store issued).
// bufA overwrite at l=2 (tag 4t+3) is gated through l=2's poll of ALL l=1
// tags, each published after reading bufA(4t+1): no live reader. Same chain
// for every gated buffer. Output WGs (wg>=128) are gated by nothing, so the
// l=4 input lives in a depth-4 ring: reuse needs a 20-phase lag, impossible
// while the WG's own l=0..3 polls chain it to the global wavefront.
// sAct is parity double-buffered: phase p+1 staging never overwrites data a
// slow wave still reads at phase p.
//
// Poll (R10/R11): whole poll loop in ONE asm volatile block -- the compiler
// cannot insert register copies inside it, removing the R6/R7 hazard class
// (reading a VGPR whose load is still in flight). Two 8-dword sample sets in
// flight; s_waitcnt vmcnt(8) retires exactly the older set (in-order
// retirement, m135); both exit paths drain vmcnt(0) before the outputs are
// visible to C code. Sampling cadence ~RT/2, no s_sleep.
// R11 fix vs R10: use the 64-bit VGPR address + `off` form (proven in R4-R9)
// instead of the voffset+saddr form, which got a VGPR pair in the saddr slot.

__device__ __forceinline__ uint16_t f2bf(float f) {
  union { float f; uint32_t u; } v; v.f = f;
  uint32_t r = v.u + 0x7FFFu + ((v.u >> 16) & 1u);   // round-to-nearest-even
  return (uint16_t)(r >> 16);
}
__device__ __forceinline__ float bf2f(uint16_t u) {
  union { uint32_t u; float f; } v; v.u = ((uint32_t)u) << 16; return v.f;
}

__device__ __forceinline__ void cstore64(u64* p, u64 v) {
  __hip_atomic_store(p, v, __ATOMIC_RELAXED, __HIP_MEMORY_SCOPE_AGENT);
}
// pack two tagged bf16 values (adjacent columns) into one 8B store
__device__ __forceinline__ u64 pack2(float v0, float v1, uint32_t tag) {
  const uint32_t w0 = (uint32_t)f2bf(v0) | (tag << 16);
  const uint32_t w1 = (uint32_t)f2bf(v1) | (tag << 16);
  return ((u64)w1 << 32) | (u64)w0;
}

__device__ __forceinline__ float dec(uint32_t w, bool relu) {
  float f = __uint_as_float(w << 16);
  return relu ? fmaxf(f, 0.f) : f;
}

// Pipelined poll of one 512-col quarter. Lane covers dwords {j*64+lane},
// j=0..7 -- each instruction reads 256B contiguous per wave (4 lines).
// On return a0..a7 hold ready data (all loads retired inside the asm).
__device__ __forceinline__ void poll2_stage(const uint32_t* __restrict__ qbase,
                                            uint32_t thr, bool relu, int lane,
                                            float* __restrict__ sdst) {
  uint32_t a0, a1, a2, a3, a4, a5, a6, a7;
  uint32_t b0, b1, b2, b3, b4, b5, b6, b7;
  u64 sacc;
  const uint32_t* p = qbase + lane;     // 64-bit flat address in VGPR pair
  asm volatile(
    // prime two full sample sets (A then B)
    "global_load_dword %[a0], %[ad], off sc0 sc1\n\t"
    "global_load_dword %[a1], %[ad], off offset:256 sc0 sc1\n\t"
    "global_load_dword %[a2], %[ad], off offset:512 sc0 sc1\n\t"
    "global_load_dword %[a3], %[ad], off offset:768 sc0 sc1\n\t"
    "global_load_dword %[a4], %[ad], off offset:1024 sc0 sc1\n\t"
    "global_load_dword %[a5], %[ad], off offset:1280 sc0 sc1\n\t"
    "global_load_dword %[a6], %[ad], off offset:1536 sc0 sc1\n\t"
    "global_load_dword %[a7], %[ad], off offset:1792 sc0 sc1\n\t"
    "global_load_dword %[b0], %[ad], off sc0 sc1\n\t"
    "global_load_dword %[b1], %[ad], off offset:256 sc0 sc1\n\t"
    "global_load_dword %[b2], %[ad], off offset:512 sc0 sc1\n\t"
    "global_load_dword %[b3], %[ad], off offset:768 sc0 sc1\n\t"
    "global_load_dword %[b4], %[ad], off offset:1024 sc0 sc1\n\t"
    "global_load_dword %[b5], %[ad], off offset:1280 sc0 sc1\n\t"
    "global_load_dword %[b6], %[ad], off offset:1536 sc0 sc1\n\t"
    "global_load_dword %[b7], %[ad], off offset:1792 sc0 sc1\n\t"
    "Lpoll%=:\n\t"
    "s_waitcnt vmcnt(8)\n\t"                 // A set retired (B in flight)
    "v_cmp_lt_u32 vcc, %[a0], %[thr]\n\t"    // lane not-ready mask
    "s_mov_b64 %[sa], vcc\n\t"
    "v_cmp_lt_u32 vcc, %[a1], %[thr]\n\t"
    "s_or_b64 %[sa], %[sa], vcc\n\t"
    "v_cmp_lt_u32 vcc, %[a2], %[thr]\n\t"
    "s_or_b64 %[sa], %[sa], vcc\n\t"
    "v_cmp_lt_u32 vcc, %[a3], %[thr]\n\t"
    "s_or_b64 %[sa], %[sa], vcc\n\t"
    "v_cmp_lt_u32 vcc, %[a4], %[thr]\n\t"
    "s_or_b64 %[sa], %[sa], vcc\n\t"
    "v_cmp_lt_u32 vcc, %[a5], %[thr]\n\t"
    "s_or_b64 %[sa], %[sa], vcc\n\t"
    "v_cmp_lt_u32 vcc, %[a6], %[thr]\n\t"
    "s_or_b64 %[sa], %[sa], vcc\n\t"
    "v_cmp_lt_u32 vcc, %[a7], %[thr]\n\t"
    "s_or_b64 %[sa], %[sa], vcc\n\t"         // SCC = any lane not ready
    "s_cbranch_scc0 LdoneA%=\n\t"
    // A stale -> reissue A
    "global_load_dword %[a0], %[ad], off sc0 sc1\n\t"
    "global_load_dword %[a1], %[ad], off offset:256 sc0 sc1\n\t"
    "global_load_dword %[a2], %[ad], off offset:512 sc0 sc1\n\t"
    "global_load_dword %[a3], %[ad], off offset:768 sc0 sc1\n\t"
    "global_load_dword %[a4], %[ad], off offset:1024 sc0 sc1\n\t"
    "global_load_dword %[a5], %[ad], off offset:1280 sc0 sc1\n\t"
    "global_load_dword %[a6], %[ad], off offset:1536 sc0 sc1\n\t"
    "global_load_dword %[a7], %[ad], off offset:1792 sc0 sc1\n\t"
    "s_waitcnt vmcnt(8)\n\t"                 // B set retired (A' in flight)
    "v_cmp_lt_u32 vcc, %[b0], %[thr]\n\t"
    "s_mov_b64 %[sa], vcc\n\t"
    "v_cmp_lt_u32 vcc, %[b1], %[thr]\n\t"
    "s_or_b64 %[sa], %[sa], vcc\n\t"
    "v_cmp_lt_u32 vcc, %[b2], %[thr]\n\t"
    "s_or_b64 %[sa], %[sa], vcc\n\t"
    "v_cmp_lt_u32 vcc, %[b3], %[thr]\n\t"
    "s_or_b64 %[sa], %[sa], vcc\n\t"
    "v_cmp_lt_u32 vcc, %[b4], %[thr]\n\t"
    "s_or_b64 %[sa], %[sa], vcc\n\t"
    "v_cmp_lt_u32 vcc, %[b5], %[thr]\n\t"
    "s_or_b64 %[sa], %[sa], vcc\n\t"
    "v_cmp_lt_u32 vcc, %[b6], %[thr]\n\t"
    "s_or_b64 %[sa], %[sa], vcc\n\t"
    "v_cmp_lt_u32 vcc, %[b7], %[thr]\n\t"
    "s_or_b64 %[sa], %[sa], vcc\n\t"
    "s_cbranch_scc0 LdoneB%=\n\t"
    // B stale -> reissue B, loop
    "global_load_dword %[b0], %[ad], off sc0 sc1\n\t"
    "global_load_dword %[b1], %[ad], off offset:256 sc0 sc1\n\t"
    "global_load_dword %[b2], %[ad], off offset:512 sc0 sc1\n\t"
    "global_load_dword %[b3], %[ad], off offset:768 sc0 sc1\n\t"
    "global_load_dword %[b4], %[ad], off offset:1024 sc0 sc1\n\t"
    "global_load_dword %[b5], %[ad], off offset:1280 sc0 sc1\n\t"
    "global_load_dword %[b6], %[ad], off offset:1536 sc0 sc1\n\t"
    "global_load_dword %[b7], %[ad], off offset:1792 sc0 sc1\n\t"
    "s_branch Lpoll%=\n\t"
    "LdoneB%=:\n\t"
    "s_waitcnt vmcnt(0)\n\t"                 // retire A' before touching a*
    "v_mov_b32 %[a0], %[b0]\n\t"
    "v_mov_b32 %[a1], %[b1]\n\t"
    "v_mov_b32 %[a2], %[b2]\n\t"
    "v_mov_b32 %[a3], %[b3]\n\t"
    "v_mov_b32 %[a4], %[b4]\n\t"
    "v_mov_b32 %[a5], %[b5]\n\t"
    "v_mov_b32 %[a6], %[b6]\n\t"
    "v_mov_b32 %[a7], %[b7]\n\t"
    "s_branch Lexit%=\n\t"
    "LdoneA%=:\n\t"
    "s_waitcnt vmcnt(0)\n\t"                 // retire outstanding B loads
    "Lexit%=:\n\t"
    : [a0]"=&v"(a0), [a1]"=&v"(a1), [a2]"=&v"(a2), [a3]"=&v"(a3),
      [a4]"=&v"(a4), [a5]"=&v"(a5), [a6]"=&v"(a6), [a7]"=&v"(a7),
      [b0]"=&v"(b0), [b1]"=&v"(b1), [b2]"=&v"(b2), [b3]"=&v"(b3),
      [b4]"=&v"(b4), [b5]"=&v"(b5), [b6]"=&v"(b6), [b7]"=&v"(b7),
      [sa]"=&s"(sacc)
    : [ad]"v"(p), [thr]"v"(thr)
    : "vcc", "scc", "memory");
  // decode: dword j covers quarter column j*64 + lane
  sdst[0 * 64 + lane] = dec(a0, relu);
  sdst[1 * 64 + lane] = dec(a1, relu);
  sdst[2 * 64 + lane] = dec(a2, relu);
  sdst[3 * 64 + lane] = dec(a3, relu);
  sdst[4 * 64 + lane] = dec(a4, relu);
  sdst[5 * 64 + lane] = dec(a5, relu);
  sdst[6 * 64 + lane] = dec(a6, relu);
  sdst[7 * 64 + lane] = dec(a7, relu);
}

__global__ void __launch_bounds__(256, 1)
rnn_persist(const float* __restrict__ x, const float* __restrict__ W0,
            const float* __restrict__ b0, const float* __restrict__ Wmid,
            const float* __restrict__ bmid, const float* __restrict__ Wf,
            const float* __restrict__ bfv, float* __restrict__ out,
            uint32_t* __restrict__ Hbuf, uint32_t* __restrict__ bufA,
            uint32_t* __restrict__ bufB, uint32_t* __restrict__ ring)
{
  __shared__ uint16_t wlds[4 * CPW * DIM];   // layers 0-3 weights, 128 KiB
  __shared__ float    sAct[2][DIM];          // parity double-buffered, 16 KiB

  const int tid  = threadIdx.x;
  const int wg   = blockIdx.x;
  const int wave = tid >> 6;
  const int lane = tid & 63;

  // each wave owns 2 adjacent output columns of every layer
  const int cidx0 = wave * 2;
  const int col0  = wg * CPW + cidx0;
  const int col1  = col0 + 1;

  // ---- stage layers 0-3 weight slice (bf16) into LDS, once ----
  for (int i = tid; i < 4 * CPW * DIM; i += 256) {
    const int l = i >> 14;           // / (CPW*DIM)
    const int r = i & 16383;
    const int k = r >> 3;            // 0..2047
    const int c = r & 7;             // 0..7
    const float* Ws = (l == 0) ? W0 : (Wmid + (size_t)(l - 1) * DIM * DIM);
    wlds[(l * CPW + c) * DIM + k] = f2bf(Ws[(size_t)k * DIM + (wg * CPW + c)]);
  }
  // ---- layer-4 weights into registers: 2 cols x 32 k-vals/lane ----
  ushort4 wf0[8], wf1[8];
  #pragma unroll
  for (int j = 0; j < 8; ++j) {
    const int k = j * 256 + lane * 4;
    wf0[j].x = f2bf(Wf[(size_t)(k + 0) * DIM + col0]);
    wf0[j].y = f2bf(Wf[(size_t)(k + 1) * DIM + col0]);
    wf0[j].z = f2bf(Wf[(size_t)(k + 2) * DIM + col0]);
    wf0[j].w = f2bf(Wf[(size_t)(k + 3) * DIM + col0]);
    wf1[j].x = f2bf(Wf[(size_t)(k + 0) * DIM + col1]);
    wf1[j].y = f2bf(Wf[(size_t)(k + 1) * DIM + col1]);
    wf1[j].z = f2bf(Wf[(size_t)(k + 2) * DIM + col1]);
    wf1[j].w = f2bf(Wf[(size_t)(k + 3) * DIM + col1]);
  }
  __syncthreads();

  float bias0[5], bias1[5];
  bias0[0] = b0[col0];              bias1[0] = b0[col1];
  bias0[1] = bmid[0 * DIM + col0];  bias1[1] = bmid[0 * DIM + col1];
  bias0[2] = bmid[1 * DIM + col0];  bias1[2] = bmid[1 * DIM + col1];
  bias0[3] = bmid[2 * DIM + col0];  bias1[3] = bmid[2 * DIM + col1];
  bias0[4] = bfv[col0];             bias1[4] = bfv[col1];

  const bool hWG = (wg < 128);   // layer-4 cols of this WG are H (else outputs)
  uint32_t ph = 0;               // global phase index = 5t + l

  for (int t = 0; t < SEQ; ++t) {
    const float* __restrict__ xrow = x + (size_t)t * HID;

    #pragma unroll
    for (int l = 0; l < 5; ++l) {
      float* __restrict__ sa = sAct[ph & 1u];

      // ============ stage this wave's quarter into sa ============
      if (l == 0) {
        if (wave < 2) {
          float* dq = sa + wave * 512 + lane * 8;
          const float4 a0 = *(const float4*)(xrow + wave * 512 + lane * 8);
          const float4 a1 = *(const float4*)(xrow + wave * 512 + lane * 8 + 4);
          *(float4*)dq       = a0;
          *(float4*)(dq + 4) = a1;
        } else {
          const int hq = wave - 2;
          poll2_stage(Hbuf + hq * 512, ((uint32_t)t) << 16, false, lane,
                      sa + 1024 + hq * 512);              // hidden: no relu
        }
      } else {
        const uint32_t* src;
        if (l == 1)      src = bufA;                          // layer-0 out
        else if (l == 2) src = bufB;                          // layer-1 out
        else if (l == 3) src = bufA;                          // layer-2 out
        else             src = ring + (size_t)(t & (RDEPTH - 1)) * DIM;
        poll2_stage(src + wave * 512,
                    (4u * (uint32_t)t + (uint32_t)l) << 16, true, lane,
                    sa + wave * 512);
      }
      __syncthreads();   // full vector staged (cross-wave join)

      // ========================== dot products ==========================
      float acc0 = 0.f, acc1 = 0.f;
      if (l < 4) {
        const uint16_t* w0p = wlds + ((l * CPW + cidx0) * DIM);
        const uint16_t* w1p = w0p + DIM;
        #pragma unroll
        for (int j = 0; j < 8; ++j) {
          const int kb = j * 256 + lane * 4;
          const float4  a  = *(const float4*)&sa[kb];
          const ushort4 wa = *(const ushort4*)(w0p + kb);
          const ushort4 wb = *(const ushort4*)(w1p + kb);
          acc0 = fmaf(a.x, bf2f(wa.x), acc0); acc1 = fmaf(a.x, bf2f(wb.x), acc1);
          acc0 = fmaf(a.y, bf2f(wa.y), acc0); acc1 = fmaf(a.y, bf2f(wb.y), acc1);
          acc0 = fmaf(a.z, bf2f(wa.z), acc0); acc1 = fmaf(a.z, bf2f(wb.z), acc1);
          acc0 = fmaf(a.w, bf2f(wa.w), acc0); acc1 = fmaf(a.w, bf2f(wb.w), acc1);
        }
      } else {
        #pragma unroll
        for (int j = 0; j < 8; ++j) {
          const int kb = j * 256 + lane * 4;
          const float4  a  = *(const float4*)&sa[kb];
          const ushort4 wa = wf0[j];
          const ushort4 wb = wf1[j];
          acc0 = fmaf(a.x, bf2f(wa.x), acc0); acc1 = fmaf(a.x, bf2f(wb.x), acc1);
          acc0 = fmaf(a.y, bf2f(wa.y), acc0); acc1 = fmaf(a.y, bf2f(wb.y), acc1);
          acc0 = fmaf(a.z, bf2f(wa.z), acc0); acc1 = fmaf(a.z, bf2f(wb.z), acc1);
          acc0 = fmaf(a.w, bf2f(wa.w), acc0); acc1 = fmaf(a.w, bf2f(wb.w), acc1);
        }
      }
      #pragma unroll
      for (int off = 32; off > 0; off >>= 1) {
        acc0 += __shfl_xor(acc0, off, 64);
        acc1 += __shfl_xor(acc1, off, 64);
      }

      // ============ publish: tagged 8B store, fire-and-continue ============
      if (lane == 0) {
        const float v0 = acc0 + bias0[l];
        const float v1 = acc1 + bias1[l];
        if (l < 3) {
          uint32_t* dst = (l == 1) ? bufB : bufA;
          cstore64((u64*)dst + (col0 >> 1),
                   pack2(v0, v1, 4u * (uint32_t)t + (uint32_t)l + 1u));
        } else if (l == 3) {
          uint32_t* dst = ring + (size_t)(t & (RDEPTH - 1)) * DIM;
          cstore64((u64*)dst + (col0 >> 1),
                   pack2(v0, v1, 4u * (uint32_t)t + 4u));
        } else if (hWG) {
          if (t < SEQ - 1) {
            cstore64((u64*)Hbuf + (col0 >> 1), pack2(v0, v1, (uint32_t)t + 1u));
          } else {
            float2 o; o.x = v0; o.y = v1;
            *(float2*)(out + col0) = o;                          // final hidden
          }
        } else {
          float2 o; o.x = v0; o.y = v1;
          *(float2*)(out + HID + (size_t)t * HID + (col0 - HID)) = o;  // outputs[t]
        }
      }
      ++ph;
    }
  }
}

extern "C" void kernel_launch(void* const* d_in, const int* in_sizes, int n_in,
                              void* d_out, int out_size, void* d_ws, size_t ws_size,
                              hipStream_t stream) {
  (void)in_sizes; (void)n_in; (void)out_size; (void)ws_size;
  const float* x    = (const float*)d_in[0];
  const float* W0   = (const float*)d_in[1];
  const float* b0   = (const float*)d_in[2];
  const float* Wmid = (const float*)d_in[3];
  const float* bmid = (const float*)d_in[4];
  const float* Wf   = (const float*)d_in[5];
  const float* bfv  = (const float*)d_in[6];
  float* out = (float*)d_out;

  uint8_t* ws = (uint8_t*)d_ws;
  uint32_t* Hbuf = (uint32_t*)(ws + 0);
  uint32_t* bufA = (uint32_t*)(ws + 4096);
  uint32_t* bufB = (uint32_t*)(ws + 12288);
  uint32_t* ring = (uint32_t*)(ws + 20480);

  // reset tags + hidden every call: {bf16 0.0, tag 0} == "H ready for t=0"
  hipMemsetAsync(d_ws, 0, 53248, stream);

  rnn_persist<<<dim3(NWG), dim3(256), 0, stream>>>(
      x, W0, b0, Wmid, bmid, Wf, bfv, out, Hbuf, bufA, bufB, ring);
}

// Round 13
// 158691.394 us; speedup vs baseline: 1.2147x; 1.1731x over previous
//
#include <hip/hip_runtime.h>
#include <hip/hip_bf16.h>
#include <stdint.h>

#define SEQ     8192
#define DIM     2048
#define HID     1024
#define NWG     256
#define CPW     8      // columns per workgroup (fused/mid layers)

typedef unsigned long long u64;
typedef __attribute__((ext_vector_type(4))) unsigned int u32x4;

// ================= Algebraic fold (R12) =================
// Reference: feat=[x,H] -> a0 = feat@W0+b0 (NO relu on H!), a_{i+1} =
// relu(a_i)@Wmid_i+b, o = relu(a3)@Wf+bf, H = o[:1024].
// Fold layer4(hidden half) into layer0:
//   a0(t) = XC(t) + relu(a3(t-1)) @ G
//   G  = Wf[:, :1024] @ W0[1024:, :]            (2048x2048, f32, precomputed)
//   XC(t) = x(t)@W0[:1024,:] + b0 + bf[:1024]@W0[1024:,:]   (t>0)
//   XC(0) = x(0)@W0[:1024,:] + b0                            (H(-1)=0 exact)
// Critical path: 4 exchanges/step (a0,a1,a2,a3) instead of 5.
// outputs[t] = relu(a3(t))@Wf[:,1024:]+bf[1024:] -- phase A of step t+1
// (off critical path); final hidden computed in an epilogue phase.
//
// XC hosting: XC[t] (2048 bf16 = 4KB) lives in the OUT buffer at outputs-row
// t+2 (exactly 4KB). XC[t] is read at step t phase A; that row is written by
// out_seq(t+2) at step t+3 phase A -- 12 phases later, transitively ordered
// by the tag chain => race-free. XC[8190],XC[8191] live in ws.
//
// ws layout: 0:a0buf 8192:a1buf 16384:a2buf 24576:a3buf (tagged u32, memset)
//            32768: XC tail rows (2 x 4KB bf16)  40960: hb[2048] f32
//            49152: G transposed, f32 [col][k], 16MB
// Tags: buffer written at step t phase l carries tag 4t+l+1 (a3: 4t+4).
// Readiness: dword >= (tag<<16) unsigned (tags monotone, max 32768 < 2^16).
// Sync machinery = R5-proven poll (issue 2x dwordx4 -> vmcnt(0)+sched_barrier
// -> check -> sleep) + parity double-buffered sAct + 1 barrier per phase.

__device__ __forceinline__ uint16_t f2bf(float f) {
  union { float f; uint32_t u; } v; v.f = f;
  uint32_t r = v.u + 0x7FFFu + ((v.u >> 16) & 1u);   // round-to-nearest-even
  return (uint16_t)(r >> 16);
}
__device__ __forceinline__ float bf2f(uint16_t u) {
  union { uint32_t u; float f; } v; v.u = ((uint32_t)u) << 16; return v.f;
}
__device__ __forceinline__ void cstore64(u64* p, u64 v) {
  __hip_atomic_store(p, v, __ATOMIC_RELAXED, __HIP_MEMORY_SCOPE_AGENT);
}
__device__ __forceinline__ u64 pack2(float v0, float v1, uint32_t tag) {
  const uint32_t w0 = (uint32_t)f2bf(v0) | (tag << 16);
  const uint32_t w1 = (uint32_t)f2bf(v1) | (tag << 16);
  return ((u64)w1 << 32) | (u64)w0;
}
__device__ __forceinline__ u32x4 cload128(const void* p) {
  u32x4 r;
  asm volatile("global_load_dwordx4 %0, %1, off sc0 sc1"
               : "=v"(r) : "v"(p) : "memory");
  return r;
}
__device__ __forceinline__ void vm_drain() {
  asm volatile("s_waitcnt vmcnt(0)" ::: "memory");
  __builtin_amdgcn_sched_barrier(0);
}

// R5-proven poll of this lane's 8 tagged u32 (32B); relu-decode into LDS.
__device__ __forceinline__ void poll_stage(const uint32_t* __restrict__ p,
                                           uint32_t thr,
                                           float* __restrict__ d) {
  u32x4 a, b;
  for (;;) {
    a = cload128(p);
    b = cload128(p + 4);
    vm_drain();
    bool ok = true;
    #pragma unroll
    for (int i = 0; i < 4; ++i) {
      ok &= (a[i] >= thr);
      ok &= (b[i] >= thr);
    }
    if (__all(ok)) break;
    __builtin_amdgcn_s_sleep(1);
  }
  #pragma unroll
  for (int i = 0; i < 4; ++i) {
    d[i]     = fmaxf(__uint_as_float(a[i] << 16), 0.f);   // relu(bf16->f32)
    d[4 + i] = fmaxf(__uint_as_float(b[i] << 16), 0.f);
  }
}

// ---------------- precompute kernels (one-time, parallel) ----------------
__global__ void k_hb(const float* __restrict__ W0, const float* __restrict__ b0,
                     const float* __restrict__ bfv, float* __restrict__ hb) {
  const int j = blockIdx.x * 256 + threadIdx.x;    // 0..2047
  float acc = b0[j];
  for (int m = 0; m < HID; ++m)
    acc = fmaf(bfv[m], W0[(size_t)(HID + m) * DIM + j], acc);
  hb[j] = acc;                                     // b0 + bf[:1024]@W0h
}

__global__ void k_G(const float* __restrict__ W0, const float* __restrict__ Wf,
                    float* __restrict__ Gt) {
  const int j = blockIdx.x * 16 + threadIdx.x;     // a0 column
  const int k = blockIdx.y * 16 + threadIdx.y;     // a3 index
  float acc = 0.f;
  for (int m = 0; m < HID; ++m)
    acc = fmaf(Wf[(size_t)k * DIM + m], W0[(size_t)(HID + m) * DIM + j], acc);
  Gt[(size_t)j * DIM + k] = acc;                   // Gt[col][k] (f32)
}

__global__ void k_XC(const float* __restrict__ x, const float* __restrict__ W0,
                     const float* __restrict__ b0, const float* __restrict__ hb,
                     float* __restrict__ out, uint16_t* __restrict__ xct) {
  const int j = blockIdx.x * 16 + threadIdx.x;     // 0..2047
  const int t = blockIdx.y * 16 + threadIdx.y;     // 0..8191
  float acc = 0.f;
  for (int m = 0; m < HID; ++m)
    acc = fmaf(x[(size_t)t * HID + m], W0[(size_t)m * DIM + j], acc);
  acc += (t > 0) ? hb[j] : b0[j];
  const uint16_t v = f2bf(acc);
  if (t <= SEQ - 3) ((uint16_t*)(out + HID + (size_t)(t + 2) * HID))[j] = v;
  else              xct[(size_t)(t - (SEQ - 2)) * DIM + j] = v;
}

// ---------------- persistent 4-phase recurrence kernel ----------------
__global__ void __launch_bounds__(256, 1)
rnn_persist(const float* __restrict__ Wmid, const float* __restrict__ bmid,
            const float* __restrict__ Wf, const float* __restrict__ bfv,
            float* __restrict__ out, uint32_t* __restrict__ a0b,
            uint32_t* __restrict__ a1b, uint32_t* __restrict__ a2b,
            uint32_t* __restrict__ a3b, const float* __restrict__ Gt,
            const uint16_t* __restrict__ xct)
{
  __shared__ uint16_t wlds[3 * CPW * DIM];   // Wmid 0..2 slices, 96 KiB
  __shared__ uint16_t wflds[4 * DIM];        // Wf out-col slice, 16 KiB
  __shared__ float    sAct[2][DIM];          // parity double-buffered, 16 KiB

  const int tid  = threadIdx.x;
  const int wg   = blockIdx.x;
  const int wave = tid >> 6;
  const int lane = tid & 63;

  const int cidx0 = wave * 2;
  const int col0  = wg * CPW + cidx0;        // fused/mid layer columns
  const int col1  = col0 + 1;
  const int ocol  = wg * 4 + wave;           // out_seq / hidden column (0..1023)

  // ---- stage Wmid slices (bf16) into LDS ----
  for (int i = tid; i < 3 * CPW * DIM; i += 256) {
    const int l = i >> 14;
    const int r = i & 16383;
    const int k = r >> 3;
    const int c = r & 7;
    wlds[(l * CPW + c) * DIM + k] =
        f2bf(Wmid[(size_t)l * DIM * DIM + (size_t)k * DIM + (wg * CPW + c)]);
  }
  // ---- stage Wf out-columns (4 per WG) into LDS ----
  for (int i = tid; i < 4 * DIM; i += 256) {
    const int w = i >> 11;
    const int k = i & 2047;
    wflds[w * DIM + k] = f2bf(Wf[(size_t)k * DIM + HID + wg * 4 + w]);
  }
  // ---- fused-layer G columns into registers (f32, 64 VGPR) ----
  float4 gf0[8], gf1[8];
  #pragma unroll
  for (int j = 0; j < 8; ++j) {
    const int k = j * 256 + lane * 4;
    gf0[j] = *(const float4*)(Gt + (size_t)col0 * DIM + k);
    gf1[j] = *(const float4*)(Gt + (size_t)col1 * DIM + k);
  }
  __syncthreads();

  float bm0[3], bm1[3];
  #pragma unroll
  for (int l = 0; l < 3; ++l) {
    bm0[l] = bmid[l * DIM + col0];
    bm1[l] = bmid[l * DIM + col1];
  }
  const float bo = bfv[HID + ocol];

  uint32_t ph = 0;   // phase index = 4t + l

  for (int t = 0; t < SEQ; ++t) {
    // =================== phase A: fused layer + out_seq(t-1) ===================
    {
      float* __restrict__ sa = sAct[ph & 1u];
      // XC word for this wave's 2 columns (prefetch; retired by poll's drain)
      const uint16_t* xcrow = (t <= SEQ - 3)
          ? (const uint16_t*)(out + HID + (size_t)(t + 2) * HID)
          : (xct + (size_t)(t - (SEQ - 2)) * DIM);
      const uint32_t xcw = *(const uint32_t*)(xcrow + col0);

      poll_stage(a3b + wave * 512 + lane * 8, (4u * (uint32_t)t) << 16,
                 sa + wave * 512 + lane * 8);
      __syncthreads();

      float acc0 = 0.f, acc1 = 0.f, accO = 0.f;
      #pragma unroll
      for (int j = 0; j < 8; ++j) {
        const int kb = j * 256 + lane * 4;
        const float4 a = *(const float4*)&sa[kb];
        const float4 g0 = gf0[j], g1 = gf1[j];
        const ushort4 wo = *(const ushort4*)(wflds + wave * DIM + kb);
        acc0 = fmaf(a.x, g0.x, acc0); acc1 = fmaf(a.x, g1.x, acc1);
        acc0 = fmaf(a.y, g0.y, acc0); acc1 = fmaf(a.y, g1.y, acc1);
        acc0 = fmaf(a.z, g0.z, acc0); acc1 = fmaf(a.z, g1.z, acc1);
        acc0 = fmaf(a.w, g0.w, acc0); acc1 = fmaf(a.w, g1.w, acc1);
        accO = fmaf(a.x, bf2f(wo.x), accO);
        accO = fmaf(a.y, bf2f(wo.y), accO);
        accO = fmaf(a.z, bf2f(wo.z), accO);
        accO = fmaf(a.w, bf2f(wo.w), accO);
      }
      #pragma unroll
      for (int off = 32; off > 0; off >>= 1) {
        acc0 += __shfl_xor(acc0, off, 64);
        acc1 += __shfl_xor(acc1, off, 64);
        accO += __shfl_xor(accO, off, 64);
      }
      if (lane == 0) {
        const float v0 = acc0 + bf2f((uint16_t)(xcw & 0xFFFFu));
        const float v1 = acc1 + bf2f((uint16_t)(xcw >> 16));
        cstore64((u64*)a0b + (col0 >> 1), pack2(v0, v1, 4u * (uint32_t)t + 1u));
        if (t > 0)
          out[HID + (size_t)(t - 1) * HID + ocol] = accO + bo;  // outputs[t-1]
      }
      ++ph;
    }
    // =================== phases B,C,D: mid layers ===================
    #pragma unroll
    for (int l = 1; l < 4; ++l) {
      float* __restrict__ sa = sAct[ph & 1u];
      const uint32_t* src = (l == 1) ? a0b : ((l == 2) ? a1b : a2b);
      uint32_t* dst = (l == 1) ? a1b : ((l == 2) ? a2b : a3b);
      poll_stage(src + wave * 512 + lane * 8,
                 (4u * (uint32_t)t + (uint32_t)l) << 16,
                 sa + wave * 512 + lane * 8);
      __syncthreads();

      float acc0 = 0.f, acc1 = 0.f;
      const uint16_t* w0p = wlds + (((l - 1) * CPW + cidx0) * DIM);
      const uint16_t* w1p = w0p + DIM;
      #pragma unroll
      for (int j = 0; j < 8; ++j) {
        const int kb = j * 256 + lane * 4;
        const float4  a  = *(const float4*)&sa[kb];
        const ushort4 wa = *(const ushort4*)(w0p + kb);
        const ushort4 wb = *(const ushort4*)(w1p + kb);
        acc0 = fmaf(a.x, bf2f(wa.x), acc0); acc1 = fmaf(a.x, bf2f(wb.x), acc1);
        acc0 = fmaf(a.y, bf2f(wa.y), acc0); acc1 = fmaf(a.y, bf2f(wb.y), acc1);
        acc0 = fmaf(a.z, bf2f(wa.z), acc0); acc1 = fmaf(a.z, bf2f(wb.z), acc1);
        acc0 = fmaf(a.w, bf2f(wa.w), acc0); acc1 = fmaf(a.w, bf2f(wb.w), acc1);
      }
      #pragma unroll
      for (int off = 32; off > 0; off >>= 1) {
        acc0 += __shfl_xor(acc0, off, 64);
        acc1 += __shfl_xor(acc1, off, 64);
      }
      if (lane == 0) {
        cstore64((u64*)dst + (col0 >> 1),
                 pack2(acc0 + bm0[l - 1], acc1 + bm1[l - 1],
                       4u * (uint32_t)t + (uint32_t)l + 1u));
      }
      ++ph;
    }
  }

  // =================== epilogue: out_seq(SEQ-1) + final hidden ===================
  {
    float* __restrict__ sa = sAct[ph & 1u];
    poll_stage(a3b + wave * 512 + lane * 8, (4u * (uint32_t)SEQ) << 16,
               sa + wave * 512 + lane * 8);
    __syncthreads();
    float accO = 0.f, accH = 0.f;
    #pragma unroll
    for (int j = 0; j < 8; ++j) {
      const int kb = j * 256 + lane * 4;
      const float4  a  = *(const float4*)&sa[kb];
      const ushort4 wo = *(const ushort4*)(wflds + wave * DIM + kb);
      accO = fmaf(a.x, bf2f(wo.x), accO);
      accO = fmaf(a.y, bf2f(wo.y), accO);
      accO = fmaf(a.z, bf2f(wo.z), accO);
      accO = fmaf(a.w, bf2f(wo.w), accO);
      accH = fmaf(a.x, Wf[(size_t)(kb + 0) * DIM + ocol], accH);
      accH = fmaf(a.y, Wf[(size_t)(kb + 1) * DIM + ocol], accH);
      accH = fmaf(a.z, Wf[(size_t)(kb + 2) * DIM + ocol], accH);
      accH = fmaf(a.w, Wf[(size_t)(kb + 3) * DIM + ocol], accH);
    }
    #pragma unroll
    for (int off = 32; off > 0; off >>= 1) {
      accO += __shfl_xor(accO, off, 64);
      accH += __shfl_xor(accH, off, 64);
    }
    if (lane == 0) {
      out[HID + (size_t)(SEQ - 1) * HID + ocol] = accO + bo;  // outputs[SEQ-1]
      out[ocol] = accH + bfv[ocol];                           // final hidden
    }
  }
}

extern "C" void kernel_launch(void* const* d_in, const int* in_sizes, int n_in,
                              void* d_out, int out_size, void* d_ws, size_t ws_size,
                              hipStream_t stream) {
  (void)in_sizes; (void)n_in; (void)out_size; (void)ws_size;
  const float* x    = (const float*)d_in[0];
  const float* W0   = (const float*)d_in[1];
  const float* b0   = (const float*)d_in[2];
  const float* Wmid = (const float*)d_in[3];
  const float* bmid = (const float*)d_in[4];
  const float* Wf   = (const float*)d_in[5];
  const float* bfv  = (const float*)d_in[6];
  float* out = (float*)d_out;

  uint8_t* ws = (uint8_t*)d_ws;
  uint32_t* a0b = (uint32_t*)(ws + 0);
  uint32_t* a1b = (uint32_t*)(ws + 8192);
  uint32_t* a2b = (uint32_t*)(ws + 16384);
  uint32_t* a3b = (uint32_t*)(ws + 24576);
  uint16_t* xct = (uint16_t*)(ws + 32768);   // XC rows 8190,8191 (8 KB)
  float*    hb  = (float*)(ws + 40960);      // 8 KB
  float*    Gt  = (float*)(ws + 49152);      // 16 MB f32

  // reset tags: a3 tag 0 == "ready for t=0" with zeros (H(-1)=0)
  hipMemsetAsync(d_ws, 0, 32768, stream);

  // one-time folds (parallel GEMMs, ~1-2 ms total)
  k_hb<<<dim3(8), dim3(256), 0, stream>>>(W0, b0, bfv, hb);
  k_G<<<dim3(128, 128), dim3(16, 16), 0, stream>>>(W0, Wf, Gt);
  k_XC<<<dim3(128, 512), dim3(16, 16), 0, stream>>>(x, W0, b0, hb, out, xct);

  rnn_persist<<<dim3(NWG), dim3(256), 0, stream>>>(
      Wmid, bmid, Wf, bfv, out, a0b, a1b, a2b, a3b, Gt, xct);
}

// Round 14
// 111462.085 us; speedup vs baseline: 1.7294x; 1.4237x over previous
//
#include <hip/hip_runtime.h>
#include <hip/hip_bf16.h>
#include <stdint.h>

#define SEQ     8192
#define DIM     2048
#define HID     1024
#define NWG     256
#define CPW     8      // columns per workgroup (fused/mid layers)

typedef unsigned long long u64;
typedef __attribute__((ext_vector_type(4))) unsigned int u32x4;

// ================= Algebraic fold (R12) + chunked single-writer lines (R13) ==
// a0(t) = XC(t) + relu(a3(t-1)) @ G ;  a_{i+1} = relu(a_i)@Wmid_i + b
// outputs[t] = relu(a3(t))@WfO+bfO (phase A of step t+1, off critical path)
// G = Wf[:,:1024]@W0[1024:,:] (f32), XC = x@W0[:1024,:]+b0(+bf@W0h for t>0),
// both precomputed by parallel kernels. 4 exchanges/step (algebraic minimum).
//
// R13 buffer layout (the new variable vs R12 -- everything else identical):
// each a-buffer = 256 chunks x 64 B; chunk c bytes 0..31 = WG c's 8 tagged
// u32 cols {bf16|tag<<16}, bytes 32..63 pad. ONE writer per 64B line (was 8
// WGs/line): WG's 4 wave-pairs gathered through LDS slots (tag-embedded,
// R8-proven LDS spin), then lanes 0..3 of wave 0 store 4x8B contiguous = one
// coalesced 32B request. Attacks write-serialization at the coherence point
// (R4 evidence: 64 writers/line catastrophic; 8/line never isolated).
//
// Gather-slot safety (no extra barrier): wave w writes sG[p&1][w] at phase
// p+2 only after its p+2 compute, which needs global p+1 data, which needs
// this WG's own chunk store at p+1 (wave0's gather at p+1), which follows
// wave0's gather-read of sG[p&1][w] at phase p. LDS ops are in-order per
// wave => no overwrite race, monotone tags => >= check is exact enough.
//
// XC hosting: XC[t] lives in OUT at outputs-row t+2 (written by out_seq(t+2)
// 12 phases after XC[t] is consumed; tag chain orders it). Tail rows in ws.
//
// ws: 0:a0b 16384:a1b 32768:a2b 49152:a3b (chunked, memset=0 => "a3 ready
// for t=0 with zeros" == H(-1)=0 exact)  65536: XC tail (8KB)
// 73728: hb (8KB)  81920: Gt f32 [col][k] (16MB)

__device__ __forceinline__ uint16_t f2bf(float f) {
  union { float f; uint32_t u; } v; v.f = f;
  uint32_t r = v.u + 0x7FFFu + ((v.u >> 16) & 1u);   // round-to-nearest-even
  return (uint16_t)(r >> 16);
}
__device__ __forceinline__ float bf2f(uint16_t u) {
  union { uint32_t u; float f; } v; v.u = ((uint32_t)u) << 16; return v.f;
}
__device__ __forceinline__ void cstore64(u64* p, u64 v) {
  __hip_atomic_store(p, v, __ATOMIC_RELAXED, __HIP_MEMORY_SCOPE_AGENT);
}
__device__ __forceinline__ u64 pack2(float v0, float v1, uint32_t tag) {
  const uint32_t w0 = (uint32_t)f2bf(v0) | (tag << 16);
  const uint32_t w1 = (uint32_t)f2bf(v1) | (tag << 16);
  return ((u64)w1 << 32) | (u64)w0;
}
__device__ __forceinline__ u32x4 cload128(const void* p) {
  u32x4 r;
  asm volatile("global_load_dwordx4 %0, %1, off sc0 sc1"
               : "=v"(r) : "v"(p) : "memory");
  return r;
}
__device__ __forceinline__ void vm_drain() {
  asm volatile("s_waitcnt vmcnt(0)" ::: "memory");
  __builtin_amdgcn_sched_barrier(0);
}

// R5-proven poll, chunked addressing: lane L covers chunk (q*64+L), reading
// its 8 tagged u32 (2x dwordx4 at +0,+16 within the lane's own 64B line).
// Decode (relu) into sAct quarter: sAct[c*8 + i] = col c*8+i.
__device__ __forceinline__ void poll_stage(const uint32_t* __restrict__ buf,
                                           int chunk, uint32_t thr,
                                           float* __restrict__ d) {
  const uint32_t* p = buf + (size_t)chunk * 16;
  u32x4 a, b;
  for (;;) {
    a = cload128(p);
    b = cload128(p + 4);
    vm_drain();
    bool ok = true;
    #pragma unroll
    for (int i = 0; i < 4; ++i) {
      ok &= (a[i] >= thr);
      ok &= (b[i] >= thr);
    }
    if (__all(ok)) break;
    __builtin_amdgcn_s_sleep(1);
  }
  #pragma unroll
  for (int i = 0; i < 4; ++i) {
    d[i]     = fmaxf(__uint_as_float(a[i] << 16), 0.f);
    d[4 + i] = fmaxf(__uint_as_float(b[i] << 16), 0.f);
  }
}

// ---------------- precompute kernels (one-time, parallel) ----------------
__global__ void k_hb(const float* __restrict__ W0, const float* __restrict__ b0,
                     const float* __restrict__ bfv, float* __restrict__ hb) {
  const int j = blockIdx.x * 256 + threadIdx.x;
  float acc = b0[j];
  for (int m = 0; m < HID; ++m)
    acc = fmaf(bfv[m], W0[(size_t)(HID + m) * DIM + j], acc);
  hb[j] = acc;
}

__global__ void k_G(const float* __restrict__ W0, const float* __restrict__ Wf,
                    float* __restrict__ Gt) {
  const int j = blockIdx.x * 16 + threadIdx.x;     // a0 column
  const int k = blockIdx.y * 16 + threadIdx.y;     // a3 index
  float acc = 0.f;
  for (int m = 0; m < HID; ++m)
    acc = fmaf(Wf[(size_t)k * DIM + m], W0[(size_t)(HID + m) * DIM + j], acc);
  Gt[(size_t)j * DIM + k] = acc;
}

__global__ void k_XC(const float* __restrict__ x, const float* __restrict__ W0,
                     const float* __restrict__ b0, const float* __restrict__ hb,
                     float* __restrict__ out, uint16_t* __restrict__ xct) {
  const int j = blockIdx.x * 16 + threadIdx.x;
  const int t = blockIdx.y * 16 + threadIdx.y;
  float acc = 0.f;
  for (int m = 0; m < HID; ++m)
    acc = fmaf(x[(size_t)t * HID + m], W0[(size_t)m * DIM + j], acc);
  acc += (t > 0) ? hb[j] : b0[j];
  const uint16_t v = f2bf(acc);
  if (t <= SEQ - 3) ((uint16_t*)(out + HID + (size_t)(t + 2) * HID))[j] = v;
  else              xct[(size_t)(t - (SEQ - 2)) * DIM + j] = v;
}

// ---------------- persistent 4-phase recurrence kernel ----------------
__global__ void __launch_bounds__(256, 1)
rnn_persist(const float* __restrict__ Wmid, const float* __restrict__ bmid,
            const float* __restrict__ Wf, const float* __restrict__ bfv,
            float* __restrict__ out, uint32_t* __restrict__ a0b,
            uint32_t* __restrict__ a1b, uint32_t* __restrict__ a2b,
            uint32_t* __restrict__ a3b, const float* __restrict__ Gt,
            const uint16_t* __restrict__ xct)
{
  __shared__ uint16_t wlds[3 * CPW * DIM];   // Wmid 0..2 slices, 96 KiB
  __shared__ uint16_t wflds[4 * DIM];        // Wf out-col slice, 16 KiB
  __shared__ float    sAct[2][DIM];          // parity double-buffered, 16 KiB
  __shared__ u64      sG[2][4];              // parity gather slots (tagged)

  const int tid  = threadIdx.x;
  const int wg   = blockIdx.x;
  const int wave = tid >> 6;
  const int lane = tid & 63;

  const int cidx0 = wave * 2;
  const int col0  = wg * CPW + cidx0;        // fused/mid layer columns
  const int col1  = col0 + 1;
  const int ocol  = wg * 4 + wave;           // out_seq / hidden column

  // ---- stage Wmid slices (bf16) into LDS ----
  for (int i = tid; i < 3 * CPW * DIM; i += 256) {
    const int l = i >> 14;
    const int r = i & 16383;
    const int k = r >> 3;
    const int c = r & 7;
    wlds[(l * CPW + c) * DIM + k] =
        f2bf(Wmid[(size_t)l * DIM * DIM + (size_t)k * DIM + (wg * CPW + c)]);
  }
  // ---- stage Wf out-columns (4 per WG) into LDS ----
  for (int i = tid; i < 4 * DIM; i += 256) {
    const int w = i >> 11;
    const int k = i & 2047;
    wflds[w * DIM + k] = f2bf(Wf[(size_t)k * DIM + HID + wg * 4 + w]);
  }
  // ---- fused-layer G columns into registers (f32, 64 VGPR) ----
  float4 gf0[8], gf1[8];
  #pragma unroll
  for (int j = 0; j < 8; ++j) {
    const int k = j * 256 + lane * 4;
    gf0[j] = *(const float4*)(Gt + (size_t)col0 * DIM + k);
    gf1[j] = *(const float4*)(Gt + (size_t)col1 * DIM + k);
  }
  if (tid < 8) sG[tid >> 2][tid & 3] = 0;
  __syncthreads();

  float bm0[3], bm1[3];
  #pragma unroll
  for (int l = 0; l < 3; ++l) {
    bm0[l] = bmid[l * DIM + col0];
    bm1[l] = bmid[l * DIM + col1];
  }
  const float bo = bfv[HID + ocol];

  uint32_t ph = 0;   // phase index = 4t + l

  for (int t = 0; t < SEQ; ++t) {
    // ============ phase A: fused layer + out_seq(t-1) ============
    {
      const int par = (int)(ph & 1u);
      float* __restrict__ sa = sAct[par];
      const uint16_t* xcrow = (t <= SEQ - 3)
          ? (const uint16_t*)(out + HID + (size_t)(t + 2) * HID)
          : (xct + (size_t)(t - (SEQ - 2)) * DIM);
      const uint32_t xcw = *(const uint32_t*)(xcrow + col0);

      poll_stage(a3b, wave * 64 + lane, (4u * (uint32_t)t) << 16,
                 sa + wave * 512 + lane * 8);
      __syncthreads();

      float acc0 = 0.f, acc1 = 0.f, accO = 0.f;
      #pragma unroll
      for (int j = 0; j < 8; ++j) {
        const int kb = j * 256 + lane * 4;
        const float4 a = *(const float4*)&sa[kb];
        const float4 g0 = gf0[j], g1 = gf1[j];
        const ushort4 wo = *(const ushort4*)(wflds + wave * DIM + kb);
        acc0 = fmaf(a.x, g0.x, acc0); acc1 = fmaf(a.x, g1.x, acc1);
        acc0 = fmaf(a.y, g0.y, acc0); acc1 = fmaf(a.y, g1.y, acc1);
        acc0 = fmaf(a.z, g0.z, acc0); acc1 = fmaf(a.z, g1.z, acc1);
        acc0 = fmaf(a.w, g0.w, acc0); acc1 = fmaf(a.w, g1.w, acc1);
        accO = fmaf(a.x, bf2f(wo.x), accO);
        accO = fmaf(a.y, bf2f(wo.y), accO);
        accO = fmaf(a.z, bf2f(wo.z), accO);
        accO = fmaf(a.w, bf2f(wo.w), accO);
      }
      #pragma unroll
      for (int off = 32; off > 0; off >>= 1) {
        acc0 += __shfl_xor(acc0, off, 64);
        acc1 += __shfl_xor(acc1, off, 64);
        accO += __shfl_xor(accO, off, 64);
      }
      const uint32_t tag = 4u * (uint32_t)t + 1u;
      if (lane == 0) {
        const float v0 = acc0 + bf2f((uint16_t)(xcw & 0xFFFFu));
        const float v1 = acc1 + bf2f((uint16_t)(xcw >> 16));
        __hip_atomic_store(&sG[par][wave], pack2(v0, v1, tag),
                           __ATOMIC_RELAXED, __HIP_MEMORY_SCOPE_WORKGROUP);
        if (t > 0)
          out[HID + (size_t)(t - 1) * HID + ocol] = accO + bo;  // outputs[t-1]
      }
      if (wave == 0 && lane < 4) {
        const uint32_t thr = tag << 16;
        u64 pv;
        for (;;) {
          pv = __hip_atomic_load(&sG[par][lane], __ATOMIC_RELAXED,
                                 __HIP_MEMORY_SCOPE_WORKGROUP);
          if ((uint32_t)pv >= thr && (uint32_t)(pv >> 32) >= thr) break;
        }
        cstore64((u64*)a0b + wg * 8 + lane, pv);   // one 32B request, 1 line
      }
      ++ph;
    }
    // ============ phases B,C,D: mid layers ============
    #pragma unroll
    for (int l = 1; l < 4; ++l) {
      const int par = (int)(ph & 1u);
      float* __restrict__ sa = sAct[par];
      const uint32_t* src = (l == 1) ? a0b : ((l == 2) ? a1b : a2b);
      uint32_t* dst = (l == 1) ? a1b : ((l == 2) ? a2b : a3b);
      poll_stage(src, wave * 64 + lane,
                 (4u * (uint32_t)t + (uint32_t)l) << 16,
                 sa + wave * 512 + lane * 8);
      __syncthreads();

      float acc0 = 0.f, acc1 = 0.f;
      const uint16_t* w0p = wlds + (((l - 1) * CPW + cidx0) * DIM);
      const uint16_t* w1p = w0p + DIM;
      #pragma unroll
      for (int j = 0; j < 8; ++j) {
        const int kb = j * 256 + lane * 4;
        const float4  a  = *(const float4*)&sa[kb];
        const ushort4 wa = *(const ushort4*)(w0p + kb);
        const ushort4 wb = *(const ushort4*)(w1p + kb);
        acc0 = fmaf(a.x, bf2f(wa.x), acc0); acc1 = fmaf(a.x, bf2f(wb.x), acc1);
        acc0 = fmaf(a.y, bf2f(wa.y), acc0); acc1 = fmaf(a.y, bf2f(wb.y), acc1);
        acc0 = fmaf(a.z, bf2f(wa.z), acc0); acc1 = fmaf(a.z, bf2f(wb.z), acc1);
        acc0 = fmaf(a.w, bf2f(wa.w), acc0); acc1 = fmaf(a.w, bf2f(wb.w), acc1);
      }
      #pragma unroll
      for (int off = 32; off > 0; off >>= 1) {
        acc0 += __shfl_xor(acc0, off, 64);
        acc1 += __shfl_xor(acc1, off, 64);
      }
      const uint32_t tag = 4u * (uint32_t)t + (uint32_t)l + 1u;
      if (lane == 0) {
        __hip_atomic_store(&sG[par][wave],
                           pack2(acc0 + bm0[l - 1], acc1 + bm1[l - 1], tag),
                           __ATOMIC_RELAXED, __HIP_MEMORY_SCOPE_WORKGROUP);
      }
      if (wave == 0 && lane < 4) {
        const uint32_t thr = tag << 16;
        u64 pv;
        for (;;) {
          pv = __hip_atomic_load(&sG[par][lane], __ATOMIC_RELAXED,
                                 __HIP_MEMORY_SCOPE_WORKGROUP);
          if ((uint32_t)pv >= thr && (uint32_t)(pv >> 32) >= thr) break;
        }
        cstore64((u64*)dst + wg * 8 + lane, pv);
      }
      ++ph;
    }
  }

  // ============ epilogue: out_seq(SEQ-1) + final hidden ============
  {
    float* __restrict__ sa = sAct[ph & 1u];
    poll_stage(a3b, wave * 64 + lane, (4u * (uint32_t)SEQ) << 16,
               sa + wave * 512 + lane * 8);
    __syncthreads();
    float accO = 0.f, accH = 0.f;
    #pragma unroll
    for (int j = 0; j < 8; ++j) {
      const int kb = j * 256 + lane * 4;
      const float4  a  = *(const float4*)&sa[kb];
      const ushort4 wo = *(const ushort4*)(wflds + wave * DIM + kb);
      accO = fmaf(a.x, bf2f(wo.x), accO);
      accO = fmaf(a.y, bf2f(wo.y), accO);
      accO = fmaf(a.z, bf2f(wo.z), accO);
      accO = fmaf(a.w, bf2f(wo.w), accO);
      accH = fmaf(a.x, Wf[(size_t)(kb + 0) * DIM + ocol], accH);
      accH = fmaf(a.y, Wf[(size_t)(kb + 1) * DIM + ocol], accH);
      accH = fmaf(a.z, Wf[(size_t)(kb + 2) * DIM + ocol], accH);
      accH = fmaf(a.w, Wf[(size_t)(kb + 3) * DIM + ocol], accH);
    }
    #pragma unroll
    for (int off = 32; off > 0; off >>= 1) {
      accO += __shfl_xor(accO, off, 64);
      accH += __shfl_xor(accH, off, 64);
    }
    if (lane == 0) {
      out[HID + (size_t)(SEQ - 1) * HID + ocol] = accO + bo;  // outputs[SEQ-1]
      out[ocol] = accH + bfv[ocol];                           // final hidden
    }
  }
}

extern "C" void kernel_launch(void* const* d_in, const int* in_sizes, int n_in,
                              void* d_out, int out_size, void* d_ws, size_t ws_size,
                              hipStream_t stream) {
  (void)in_sizes; (void)n_in; (void)out_size; (void)ws_size;
  const float* x    = (const float*)d_in[0];
  const float* W0   = (const float*)d_in[1];
  const float* b0   = (const float*)d_in[2];
  const float* Wmid = (const float*)d_in[3];
  const float* bmid = (const float*)d_in[4];
  const float* Wf   = (const float*)d_in[5];
  const float* bfv  = (const float*)d_in[6];
  float* out = (float*)d_out;

  uint8_t* ws = (uint8_t*)d_ws;
  uint32_t* a0b = (uint32_t*)(ws + 0);
  uint32_t* a1b = (uint32_t*)(ws + 16384);
  uint32_t* a2b = (uint32_t*)(ws + 32768);
  uint32_t* a3b = (uint32_t*)(ws + 49152);
  uint16_t* xct = (uint16_t*)(ws + 65536);   // XC rows 8190,8191
  float*    hb  = (float*)(ws + 73728);
  float*    Gt  = (float*)(ws + 81920);      // 16 MB f32

  // reset tags: chunked a-buffers zero => "a3 ready for t=0 with zeros"
  hipMemsetAsync(d_ws, 0, 65536, stream);

  // one-time folds (parallel GEMMs, ~1-2 ms total)
  k_hb<<<dim3(8), dim3(256), 0, stream>>>(W0, b0, bfv, hb);
  k_G<<<dim3(128, 128), dim3(16, 16), 0, stream>>>(W0, Wf, Gt);
  k_XC<<<dim3(128, 512), dim3(16, 16), 0, stream>>>(x, W0, b0, hb, out, xct);

  rnn_persist<<<dim3(NWG), dim3(256), 0, stream>>>(
      Wmid, bmid, Wf, bfv, out, a0b, a1b, a2b, a3b, Gt, xct);
}